// Round 1
// baseline (307.962 us; speedup 1.0000x reference)
//
#include <hip/hip_runtime.h>
#include <hip/hip_bf16.h>

// ---------------------------------------------------------------------------
// LucasKANLayer: y[b,o] = sum_i sum_d L_d(tanh(x[b,i])) * C[i,o,d]
// == GEMM: A[8192 x 8192] (bf16, A[b, i*8+d] = L_d(tanh(x[b,i])))
//        @ B[8192 x 1024] (bf16, stored transposed Bt[o, i*8+d] = C[i,o,d])
// 137.4 GFLOP -> bf16 MFMA, m97-style 128x128x64 tile w/ global_load_lds.
// ---------------------------------------------------------------------------

typedef __attribute__((ext_vector_type(8)))  short  short8;   // bf16x8 MFMA frag
typedef __attribute__((ext_vector_type(8)))  unsigned short ushort8;
typedef __attribute__((ext_vector_type(4)))  float  float4v;

#define M_DIM 8192
#define I_DIM 1024
#define O_DIM 1024
#define K_DIM 8192   // I_DIM * 8
#define BM 128
#define BN 128
#define BK 64

// round-to-nearest-even fp32 -> bf16 bits
__device__ __forceinline__ unsigned short f2bf(float f) {
    unsigned int u = __float_as_uint(f);
    u += 0x7FFFu + ((u >> 16) & 1u);
    return (unsigned short)(u >> 16);
}

__device__ __forceinline__ void lucas8(float t, float* L) {
    L[0] = 2.0f; L[1] = t;
    #pragma unroll
    for (int d = 2; d < 8; ++d) L[d] = t * L[d - 1] + L[d - 2];
}

// ---- prep A: A[b][i*8+d] = L_d(tanh(x[b,i])) as bf16, K-contiguous rows ----
__global__ __launch_bounds__(256) void prep_a_kernel(const float* __restrict__ x,
                                                     unsigned short* __restrict__ A,
                                                     int total) {
    int idx = blockIdx.x * 256 + threadIdx.x;   // one (b,i) per thread
    if (idx >= total) return;
    float t = tanhf(x[idx]);
    float L[8];
    lucas8(t, L);
    ushort8 v;
    #pragma unroll
    for (int d = 0; d < 8; ++d) v[d] = f2bf(L[d]);
    int b = idx >> 10;          // /1024
    int i = idx & 1023;
    *(ushort8*)(A + (size_t)b * K_DIM + i * 8) = v;   // 16B coalesced store
}

// ---- prep B: Bt[o][i*8+d] = coeffs[i][o][d] as bf16 ----
__global__ __launch_bounds__(256) void prep_b_kernel(const float* __restrict__ c,
                                                     unsigned short* __restrict__ Bt) {
    int idx = blockIdx.x * 256 + threadIdx.x;   // one (i,o) per thread
    int i = idx >> 10;
    int o = idx & 1023;                          // consecutive threads: o fast -> coalesced reads
    const float* src = c + (size_t)i * 8192 + o * 8;
    float4v lo = *(const float4v*)(src);
    float4v hi = *(const float4v*)(src + 4);
    ushort8 v;
    v[0] = f2bf(lo[0]); v[1] = f2bf(lo[1]); v[2] = f2bf(lo[2]); v[3] = f2bf(lo[3]);
    v[4] = f2bf(hi[0]); v[5] = f2bf(hi[1]); v[6] = f2bf(hi[2]); v[7] = f2bf(hi[3]);
    *(ushort8*)(Bt + (size_t)o * K_DIM + i * 8) = v;
}

// ---- GEMM: out[m][n] = sum_k A[m][k] * Bt[n][k] ----
__global__ __launch_bounds__(256, 2) void gemm_kernel(const unsigned short* __restrict__ A,
                                                      const unsigned short* __restrict__ Bt,
                                                      float* __restrict__ out) {
    __shared__ unsigned short As[BM * BK];   // [m][k], 16 KB
    __shared__ unsigned short Bs[BN * BK];   // [n][k], 16 KB

    const int tid  = threadIdx.x;
    const int lane = tid & 63;
    const int wave = tid >> 6;
    const int n0 = blockIdx.x * BN;
    const int m0 = blockIdx.y * BM;

    const int wm0 = (wave >> 1) * 64;   // wave's 64x64 sub-tile
    const int wn0 = (wave & 1) * 64;
    const int l16  = lane & 15;
    const int quad = lane >> 4;

    // staging: per round a wave covers 8 rows x 64 k (1 KB). lane -> row/col:
    const int srow = lane >> 3;          // 0..7
    const int scol = (lane & 7) * 8;     // k offset, 16B chunks

    float4v acc[4][4];
    const float4v zero = {0.f, 0.f, 0.f, 0.f};
    #pragma unroll
    for (int a = 0; a < 4; ++a)
        #pragma unroll
        for (int b = 0; b < 4; ++b) acc[a][b] = zero;

    for (int kt = 0; kt < K_DIM; kt += BK) {
        #pragma unroll
        for (int r = 0; r < 4; ++r) {
            const int rowb = r * 32 + wave * 8;   // wave-uniform row base
            const unsigned short* gA = A + (size_t)(m0 + rowb + srow) * K_DIM + kt + scol;
            __builtin_amdgcn_global_load_lds(
                (const __attribute__((address_space(1))) unsigned int*)gA,
                (__attribute__((address_space(3))) unsigned int*)&As[rowb * BK],
                16, 0, 0);
            const unsigned short* gB = Bt + (size_t)(n0 + rowb + srow) * K_DIM + kt + scol;
            __builtin_amdgcn_global_load_lds(
                (const __attribute__((address_space(1))) unsigned int*)gB,
                (__attribute__((address_space(3))) unsigned int*)&Bs[rowb * BK],
                16, 0, 0);
        }
        __syncthreads();   // drains vmcnt(0) before barrier

        #pragma unroll
        for (int k2 = 0; k2 < 2; ++k2) {
            short8 af[4], bf[4];
            #pragma unroll
            for (int t = 0; t < 4; ++t) {
                af[t] = *(const short8*)&As[(wm0 + t * 16 + l16) * BK + k2 * 32 + quad * 8];
                bf[t] = *(const short8*)&Bs[(wn0 + t * 16 + l16) * BK + k2 * 32 + quad * 8];
            }
            #pragma unroll
            for (int tm = 0; tm < 4; ++tm)
                #pragma unroll
                for (int tn = 0; tn < 4; ++tn)
                    acc[tm][tn] = __builtin_amdgcn_mfma_f32_16x16x32_bf16(
                        af[tm], bf[tn], acc[tm][tn], 0, 0, 0);
        }
        __syncthreads();
    }

    // epilogue: D[row=(lane>>4)*4+r][col=lane&15]
    #pragma unroll
    for (int tm = 0; tm < 4; ++tm) {
        #pragma unroll
        for (int tn = 0; tn < 4; ++tn) {
            const int col = n0 + wn0 + tn * 16 + l16;
            #pragma unroll
            for (int r = 0; r < 4; ++r) {
                const int row = m0 + wm0 + tm * 16 + quad * 4 + r;
                out[(size_t)row * O_DIM + col] = acc[tm][tn][r];
            }
        }
    }
}

// ---- fallback (only if workspace is absurdly small): direct fp32 ----
__global__ __launch_bounds__(256) void naive_kernel(const float* __restrict__ x,
                                                    const float* __restrict__ c,
                                                    float* __restrict__ out) {
    int idx = blockIdx.x * 256 + threadIdx.x;   // one (b,o)
    int b = idx >> 10;
    int o = idx & 1023;
    const float* xb = x + (size_t)b * I_DIM;
    float acc = 0.f;
    for (int i = 0; i < I_DIM; ++i) {
        float t = tanhf(xb[i]);
        float L[8];
        lucas8(t, L);
        const float* cc = c + (size_t)i * 8192 + o * 8;
        #pragma unroll
        for (int d = 0; d < 8; ++d) acc += L[d] * cc[d];
    }
    out[idx] = acc;
}

extern "C" void kernel_launch(void* const* d_in, const int* in_sizes, int n_in,
                              void* d_out, int out_size, void* d_ws, size_t ws_size,
                              hipStream_t stream) {
    const float* x      = (const float*)d_in[0];
    const float* coeffs = (const float*)d_in[1];
    float* out = (float*)d_out;

    const size_t btBytes   = (size_t)O_DIM * K_DIM * sizeof(unsigned short);   // 16 MiB
    const size_t rowBytes  = (size_t)K_DIM * sizeof(unsigned short);           // 16 KiB / row

    if (ws_size >= btBytes + 128 * rowBytes) {
        unsigned short* Bt = (unsigned short*)d_ws;
        unsigned short* A  = (unsigned short*)((char*)d_ws + btBytes);

        size_t rows_cap = (ws_size - btBytes) / rowBytes;
        rows_cap = (rows_cap / 128) * 128;
        if (rows_cap > M_DIM) rows_cap = M_DIM;

        prep_b_kernel<<<(I_DIM * O_DIM) / 256, 256, 0, stream>>>(coeffs, Bt);

        for (size_t r0 = 0; r0 < M_DIM; r0 += rows_cap) {
            size_t rows = M_DIM - r0;
            if (rows > rows_cap) rows = rows_cap;
            prep_a_kernel<<<(int)((rows * I_DIM) / 256), 256, 0, stream>>>(
                x + r0 * I_DIM, A, (int)(rows * I_DIM));
            dim3 grid(O_DIM / BN, (unsigned)(rows / BM));
            gemm_kernel<<<grid, 256, 0, stream>>>(A, Bt, out + r0 * O_DIM);
        }
    } else {
        naive_kernel<<<(M_DIM * O_DIM) / 256, 256, 0, stream>>>(x, coeffs, out);
    }
}

// Round 2
// 259.158 us; speedup vs baseline: 1.1883x; 1.1883x over previous
//
#include <hip/hip_runtime.h>
#include <hip/hip_bf16.h>

// ---------------------------------------------------------------------------
// LucasKANLayer fused: y[b,o] = sum_i sum_d L_d(tanh(x[b,i])) * C[i,o,d]
// R2: fuse Lucas expansion into the GEMM (A never materialized), XOR-swizzled
// LDS (kills 16-way bank conflicts), double-buffered B/T staging with
// prefetch issued during the MFMA phase, single GEMM dispatch (512 blocks).
// ---------------------------------------------------------------------------

typedef __attribute__((ext_vector_type(8)))  short  short8;    // bf16x8 MFMA frag
typedef __attribute__((ext_vector_type(4)))  unsigned short ushort4v;
typedef __attribute__((ext_vector_type(8)))  unsigned short ushort8;
typedef __attribute__((ext_vector_type(4)))  float  float4v;
typedef __attribute__((ext_vector_type(4)))  unsigned int uint4v;

#define M_DIM 8192
#define I_DIM 1024
#define O_DIM 1024
#define K_DIM 8192   // I_DIM * 8
#define BM 128
#define BN 128
#define BK 64        // 8 i-values per K-step

// round-to-nearest-even fp32 -> bf16 bits (used in prep kernels)
__device__ __forceinline__ unsigned short f2bf(float f) {
    unsigned int u = __float_as_uint(f);
    u += 0x7FFFu + ((u >> 16) & 1u);
    return (unsigned short)(u >> 16);
}

// ---- prep T: T[b][i] = bf16(tanh(x[b,i])), 4 elements/thread ----
__global__ __launch_bounds__(256) void prep_t_kernel(const float* __restrict__ x,
                                                     unsigned short* __restrict__ T) {
    int idx = (blockIdx.x * 256 + threadIdx.x) * 4;
    float4v v = *(const float4v*)(x + idx);
    ushort4v o;
    o[0] = f2bf(tanhf(v[0]));
    o[1] = f2bf(tanhf(v[1]));
    o[2] = f2bf(tanhf(v[2]));
    o[3] = f2bf(tanhf(v[3]));
    *(ushort4v*)(T + idx) = o;
}

// ---- prep B: Bt[o][i*8+d] = bf16(coeffs[i][o][d]) ----
__global__ __launch_bounds__(256) void prep_b_kernel(const float* __restrict__ c,
                                                     unsigned short* __restrict__ Bt) {
    int idx = blockIdx.x * 256 + threadIdx.x;   // one (i,o) per thread
    int i = idx >> 10;
    int o = idx & 1023;
    const float* src = c + (size_t)i * 8192 + o * 8;
    float4v lo = *(const float4v*)(src);
    float4v hi = *(const float4v*)(src + 4);
    ushort8 v;
    v[0] = f2bf(lo[0]); v[1] = f2bf(lo[1]); v[2] = f2bf(lo[2]); v[3] = f2bf(lo[3]);
    v[4] = f2bf(hi[0]); v[5] = f2bf(hi[1]); v[6] = f2bf(hi[2]); v[7] = f2bf(hi[3]);
    *(ushort8*)(Bt + (size_t)o * K_DIM + i * 8) = v;
}

// ---- fused GEMM: out[m][n] = sum_k A[m][k] * Bt[n][k], A expanded from T ----
// LDS chunk swizzle: 16B chunk c of row r lives at slot (c ^ (r&7)).
__global__ __launch_bounds__(256, 2) void gemm_kernel(const unsigned short* __restrict__ T,
                                                      const unsigned short* __restrict__ Bt,
                                                      float* __restrict__ out) {
    __shared__ unsigned short As[BM * BK];        // 16 KB, swizzled
    __shared__ unsigned short Bs[2][BN * BK];     // 32 KB, swizzled, dbuf
    __shared__ unsigned short Ts[2][BM * 8];      // 4 KB, dbuf (8 i-values/row)

    const int tid  = threadIdx.x;
    const int lane = tid & 63;
    const int wave = tid >> 6;
    const int m0 = blockIdx.x * BM;   // grid.x = m: 8 n-blocks of a stripe are %8-congruent -> same XCD
    const int n0 = blockIdx.y * BN;

    const int wm0  = (wave >> 1) * 64;
    const int wn0  = (wave & 1) * 64;
    const int l16  = lane & 15;
    const int quad = lane >> 4;

    // staging lane mapping (B): row-sub srow, global chunk XOR-swizzled
    const int srow   = lane >> 3;            // 0..7
    const int il     = lane & 7;             // also expansion i-local
    const int gchunk = il ^ srow;            // global 16B chunk this lane fetches

    float4v acc[4][4];
    const float4v zero = {0.f, 0.f, 0.f, 0.f};
    #pragma unroll
    for (int a = 0; a < 4; ++a)
        #pragma unroll
        for (int b = 0; b < 4; ++b) acc[a][b] = zero;

    // ---- prologue: stage Bs[0] (kt=0) and Ts[0] (i0=0) ----
    #pragma unroll
    for (int r = 0; r < 4; ++r) {
        const int rowb = r * 32 + wave * 8;
        const unsigned short* gB = Bt + (size_t)(n0 + rowb + srow) * K_DIM + gchunk * 8;
        __builtin_amdgcn_global_load_lds(
            (const __attribute__((address_space(1))) unsigned int*)gB,
            (__attribute__((address_space(3))) unsigned int*)&Bs[0][rowb * BK], 16, 0, 0);
    }
    if (wave < 2) {
        const unsigned short* gT = T + (size_t)(m0 + wave * 64 + lane) * I_DIM;
        __builtin_amdgcn_global_load_lds(
            (const __attribute__((address_space(1))) unsigned int*)gT,
            (__attribute__((address_space(3))) unsigned int*)&Ts[0][wave * 64 * 8], 16, 0, 0);
    }
    __syncthreads();

    int cur = 0;
    for (int kt = 0; kt < K_DIM; kt += BK) {
        // ---- phase E: expand Ts[cur] -> As (Lucas recurrence, bf16 pack) ----
        #pragma unroll
        for (int j = 0; j < 4; ++j) {
            const int row = wave * 32 + j * 8 + srow;          // row & 7 == srow
            const unsigned int tb = Ts[cur][row * 8 + il];
            const float t = __uint_as_float(tb << 16);
            const float L2v = fmaf(t, t, 2.0f);
            const float L3v = fmaf(t, L2v, t);
            const float L4v = fmaf(t, L3v, L2v);
            const float L5v = fmaf(t, L4v, L3v);
            const float L6v = fmaf(t, L5v, L4v);
            const float L7v = fmaf(t, L6v, L5v);
            // round-half-up to bf16, pack pairs with v_perm
            const unsigned int u2 = __float_as_uint(L2v) + 0x8000u;
            const unsigned int u3 = __float_as_uint(L3v) + 0x8000u;
            const unsigned int u4 = __float_as_uint(L4v) + 0x8000u;
            const unsigned int u5 = __float_as_uint(L5v) + 0x8000u;
            const unsigned int u6 = __float_as_uint(L6v) + 0x8000u;
            const unsigned int u7 = __float_as_uint(L7v) + 0x8000u;
            uint4v pk;
            pk[0] = 0x4000u | (tb << 16);                      // L0=2.0, L1=t (already bf16)
            pk[1] = __builtin_amdgcn_perm(u3, u2, 0x07060302);
            pk[2] = __builtin_amdgcn_perm(u5, u4, 0x07060302);
            pk[3] = __builtin_amdgcn_perm(u7, u6, 0x07060302);
            *(uint4v*)&As[row * BK + ((il ^ srow) * 8)] = pk;  // swizzled 16B store
        }
        __syncthreads();   // barrier A: As ready

        // ---- phase M: prefetch next step into other buffers, then MFMA ----
        const int nxt = cur ^ 1;
        if (kt + BK < K_DIM) {
            #pragma unroll
            for (int r = 0; r < 4; ++r) {
                const int rowb = r * 32 + wave * 8;
                const unsigned short* gB = Bt + (size_t)(n0 + rowb + srow) * K_DIM
                                              + (kt + BK) + gchunk * 8;
                __builtin_amdgcn_global_load_lds(
                    (const __attribute__((address_space(1))) unsigned int*)gB,
                    (__attribute__((address_space(3))) unsigned int*)&Bs[nxt][rowb * BK], 16, 0, 0);
            }
            if (wave < 2) {
                const unsigned short* gT = T + (size_t)(m0 + wave * 64 + lane) * I_DIM
                                             + (kt + BK) / 8;
                __builtin_amdgcn_global_load_lds(
                    (const __attribute__((address_space(1))) unsigned int*)gT,
                    (__attribute__((address_space(3))) unsigned int*)&Ts[nxt][wave * 64 * 8], 16, 0, 0);
            }
        }

        #pragma unroll
        for (int k2 = 0; k2 < 2; ++k2) {
            short8 af[4], bfr[4];
            #pragma unroll
            for (int t = 0; t < 4; ++t) {
                const int arow = wm0 + t * 16 + l16;
                af[t]  = *(const short8*)&As[arow * BK + (((k2 * 4 + quad) ^ (l16 & 7)) * 8)];
                const int brow = wn0 + t * 16 + l16;
                bfr[t] = *(const short8*)&Bs[cur][brow * BK + (((k2 * 4 + quad) ^ (l16 & 7)) * 8)];
            }
            #pragma unroll
            for (int tm = 0; tm < 4; ++tm)
                #pragma unroll
                for (int tn = 0; tn < 4; ++tn)
                    acc[tm][tn] = __builtin_amdgcn_mfma_f32_16x16x32_bf16(
                        af[tm], bfr[tn], acc[tm][tn], 0, 0, 0);
        }
        __syncthreads();   // barrier B: drains prefetch, protects As WAR
        cur = nxt;
    }

    // ---- epilogue: D[row=(lane>>4)*4+r][col=lane&15] (verified R1) ----
    #pragma unroll
    for (int tm = 0; tm < 4; ++tm) {
        #pragma unroll
        for (int tn = 0; tn < 4; ++tn) {
            const int col = n0 + wn0 + tn * 16 + l16;
            #pragma unroll
            for (int r = 0; r < 4; ++r) {
                const int row = m0 + wm0 + tm * 16 + quad * 4 + r;
                out[(size_t)row * O_DIM + col] = acc[tm][tn][r];
            }
        }
    }
}

// ---- fallback (tiny workspace): direct fp32 ----
__global__ __launch_bounds__(256) void naive_kernel(const float* __restrict__ x,
                                                    const float* __restrict__ c,
                                                    float* __restrict__ out) {
    int idx = blockIdx.x * 256 + threadIdx.x;   // one (b,o)
    int b = idx >> 10;
    int o = idx & 1023;
    const float* xb = x + (size_t)b * I_DIM;
    float acc = 0.f;
    for (int i = 0; i < I_DIM; ++i) {
        float t = tanhf(xb[i]);
        float L[8];
        L[0] = 2.0f; L[1] = t;
        #pragma unroll
        for (int d = 2; d < 8; ++d) L[d] = t * L[d - 1] + L[d - 2];
        const float* cc = c + (size_t)i * 8192 + o * 8;
        #pragma unroll
        for (int d = 0; d < 8; ++d) acc += L[d] * cc[d];
    }
    out[idx] = acc;
}

extern "C" void kernel_launch(void* const* d_in, const int* in_sizes, int n_in,
                              void* d_out, int out_size, void* d_ws, size_t ws_size,
                              hipStream_t stream) {
    const float* x      = (const float*)d_in[0];
    const float* coeffs = (const float*)d_in[1];
    float* out = (float*)d_out;

    const size_t btBytes = (size_t)O_DIM * K_DIM * sizeof(unsigned short);   // 16 MiB
    const size_t tBytes  = (size_t)M_DIM * I_DIM * sizeof(unsigned short);   // 16 MiB

    if (ws_size >= btBytes + tBytes) {
        unsigned short* Bt = (unsigned short*)d_ws;
        unsigned short* T  = (unsigned short*)((char*)d_ws + btBytes);

        prep_b_kernel<<<(I_DIM * O_DIM) / 256, 256, 0, stream>>>(coeffs, Bt);
        prep_t_kernel<<<(M_DIM * I_DIM) / (4 * 256), 256, 0, stream>>>(x, T);

        dim3 grid(M_DIM / BM, O_DIM / BN);   // (64, 8): m fast -> XCD-local T reuse
        gemm_kernel<<<grid, 256, 0, stream>>>(T, Bt, out);
    } else {
        naive_kernel<<<(M_DIM * O_DIM) / 256, 256, 0, stream>>>(x, coeffs, out);
    }
}